// Round 3
// baseline (36.554 us; speedup 1.0000x reference)
//
#include <hip/hip_runtime.h>
#include <math.h>

// Problem size: B*C*H*W = 64*1*512*512
#define N_TOTAL 16777216
#define ACC_COUNT 5       // sx, st, sx2, sxt, sbce   (st2 == st since t in {0,1})
#define MAX_BLOCKS 2048

__global__ __launch_bounds__(256) void loss_reduce_kernel(
    const float4* __restrict__ x4,
    const float4* __restrict__ t4,
    float* __restrict__ partials,   // SoA: partials[k*MAX_BLOCKS + blockIdx.x]
    int n4)
{
    float sx = 0.f, st = 0.f, sx2 = 0.f, sxt = 0.f, sb = 0.f;

    const int tid    = blockIdx.x * blockDim.x + threadIdx.x;
    const int stride = gridDim.x * blockDim.x;

    int i = tid;

    // ---- main loop: 4-way unrolled => 8 independent 16B loads in flight ----
    for (; i + 3 * stride < n4; i += 4 * stride) {
        float4 xv0 = x4[i];
        float4 xv1 = x4[i + stride];
        float4 xv2 = x4[i + 2 * stride];
        float4 xv3 = x4[i + 3 * stride];
        float4 tv0 = t4[i];
        float4 tv1 = t4[i + stride];
        float4 tv2 = t4[i + 2 * stride];
        float4 tv3 = t4[i + 3 * stride];

        float4 xa[4] = {xv0, xv1, xv2, xv3};
        float4 ta[4] = {tv0, tv1, tv2, tv3};

        #pragma unroll
        for (int u = 0; u < 4; ++u) {
            const float* xp = reinterpret_cast<const float*>(&xa[u]);
            const float* tp = reinterpret_cast<const float*>(&ta[u]);
            #pragma unroll
            for (int j = 0; j < 4; ++j) {
                float x = xp[j];
                float t = tp[j];
                sx += x;
                st += t;
                sx2 = fmaf(x, x, sx2);
                sxt = fmaf(x, t, sxt);
                float lp  = fmaxf(__logf(x), -100.0f);
                float l1p = fmaxf(__logf(1.0f - x), -100.0f);
                // t*lp + (1-t)*l1p = l1p + t*(lp - l1p)
                sb += l1p;
                sb = fmaf(t, lp - l1p, sb);
            }
        }
    }

    // ---- tail ----
    for (; i < n4; i += stride) {
        float4 xv = x4[i];
        float4 tv = t4[i];
        const float* xp = reinterpret_cast<const float*>(&xv);
        const float* tp = reinterpret_cast<const float*>(&tv);
        #pragma unroll
        for (int j = 0; j < 4; ++j) {
            float x = xp[j];
            float t = tp[j];
            sx += x;
            st += t;
            sx2 = fmaf(x, x, sx2);
            sxt = fmaf(x, t, sxt);
            float lp  = fmaxf(__logf(x), -100.0f);
            float l1p = fmaxf(__logf(1.0f - x), -100.0f);
            sb += l1p;
            sb = fmaf(t, lp - l1p, sb);
        }
    }

    // ---- wave (64-lane) reduction ----
    #pragma unroll
    for (int off = 32; off > 0; off >>= 1) {
        sx  += __shfl_down(sx,  off);
        st  += __shfl_down(st,  off);
        sx2 += __shfl_down(sx2, off);
        sxt += __shfl_down(sxt, off);
        sb  += __shfl_down(sb,  off);
    }

    // ---- block reduction across 4 waves ----
    __shared__ float lds[4][ACC_COUNT];
    int lane = threadIdx.x & 63;
    int wid  = threadIdx.x >> 6;
    if (lane == 0) {
        lds[wid][0] = sx;  lds[wid][1] = st;  lds[wid][2] = sx2;
        lds[wid][3] = sxt; lds[wid][4] = sb;
    }
    __syncthreads();

    if (threadIdx.x < ACC_COUNT) {
        int k = threadIdx.x;
        float v = lds[0][k] + lds[1][k] + lds[2][k] + lds[3][k];
        partials[k * MAX_BLOCKS + blockIdx.x] = v;   // SoA, no atomics
    }
}

__global__ __launch_bounds__(256) void loss_finalize_kernel(
    const float* __restrict__ partials,
    float* __restrict__ out,
    int nblocks)
{
    double a[ACC_COUNT] = {0, 0, 0, 0, 0};

    // coalesced SoA reads; 5 independent load streams per iteration
    for (int r = threadIdx.x; r < nblocks; r += blockDim.x) {
        #pragma unroll
        for (int k = 0; k < ACC_COUNT; ++k)
            a[k] += (double)partials[k * MAX_BLOCKS + r];
    }

    #pragma unroll
    for (int off = 32; off > 0; off >>= 1) {
        #pragma unroll
        for (int k = 0; k < ACC_COUNT; ++k)
            a[k] += __shfl_down(a[k], off);
    }

    __shared__ double lds[4][ACC_COUNT];
    int lane = threadIdx.x & 63;
    int wid  = threadIdx.x >> 6;
    if (lane == 0) {
        #pragma unroll
        for (int k = 0; k < ACC_COUNT; ++k) lds[wid][k] = a[k];
    }
    __syncthreads();

    if (threadIdx.x == 0) {
        double sx  = lds[0][0] + lds[1][0] + lds[2][0] + lds[3][0];
        double st  = lds[0][1] + lds[1][1] + lds[2][1] + lds[3][1];
        double sx2 = lds[0][2] + lds[1][2] + lds[2][2] + lds[3][2];
        double sxt = lds[0][3] + lds[1][3] + lds[2][3] + lds[3][3];
        double sb  = lds[0][4] + lds[1][4] + lds[2][4] + lds[3][4];

        const double n = (double)N_TOTAL;

        // BCE
        double bce = -sb / n;

        // NCC (Σt² == Σt exactly, since t ∈ {0,1})
        double xm = sx / n;
        double tm = st / n;
        double xs = sqrt((sx2 - sx * sx / n) / (n - 1.0));
        double ts = sqrt((st  - st * st / n) / (n - 1.0));
        double ncc = (sxt - n * xm * tm) / (xs * ts * n);

        // Tversky
        const double beta = 0.1, adding = 1.0;
        double TP = sxt;
        double FP = sx - sxt;
        double FN = st - sxt;
        double tversky = (TP + adding) / (TP + beta * FP + (1.0 - beta) * FN + adding);

        const double alpha = 0.5;
        double res = (1.0 - (alpha * ncc + (1.0 - alpha) * tversky)) * bce;

        out[0] = (float)res;
    }
}

extern "C" void kernel_launch(void* const* d_in, const int* in_sizes, int n_in,
                              void* d_out, int out_size, void* d_ws, size_t ws_size,
                              hipStream_t stream)
{
    const float* x = (const float*)d_in[0];
    const float* t = (const float*)d_in[1];
    float* out = (float*)d_out;
    float* partials = (float*)d_ws;

    int n  = in_sizes[0];
    int n4 = n / 4;

    const int block = 256;
    int grid = (n4 + block - 1) / block;
    if (grid > MAX_BLOCKS) grid = MAX_BLOCKS;

    loss_reduce_kernel<<<grid, block, 0, stream>>>(
        (const float4*)x, (const float4*)t, partials, n4);
    loss_finalize_kernel<<<1, block, 0, stream>>>(partials, out, grid);
}

// Round 4
// 32.027 us; speedup vs baseline: 1.1414x; 1.1414x over previous
//
#include <hip/hip_runtime.h>
#include <math.h>

// Problem size: B*C*H*W = 64*1*512*512
#define N_TOTAL 16777216
#define ACC_COUNT 5       // sx, st, sx2, sxt, sb(log2-space)   (st2 == st since t in {0,1})
#define MAX_BLOCKS 2048

// Per-element body. t is EXACTLY 0.0f or 1.0f, so the BCE blend
//   t*max(log x,-100) + (1-t)*max(log(1-x),-100)
// selects exactly one term:  max(log(t ? x : 1-x), -100).
// Work in log2 space (hardware v_log_f32) and scale by ln2 once at the end:
//   max(log(a),-100) = ln2 * max(log2(a), -100/ln2)
#define ELEM_BODY(x, t)                                        \
    do {                                                       \
        float omx = 1.0f - (x);                                \
        sx += (x);                                             \
        st += (t);                                             \
        sx2 = fmaf((x), (x), sx2);                             \
        sxt = fmaf((x), (t), sxt);                             \
        float arg = fmaf((t), (x) - omx, omx); /* t?x:1-x */   \
        float l2  = fmaxf(__log2f(arg), -144.26950408889634f); \
        sb += l2;                                              \
    } while (0)

__global__ __launch_bounds__(256) void loss_reduce_kernel(
    const float4* __restrict__ x4,
    const float4* __restrict__ t4,
    float* __restrict__ partials,   // SoA: partials[k*MAX_BLOCKS + blockIdx.x]
    int n4)
{
    float sx = 0.f, st = 0.f, sx2 = 0.f, sxt = 0.f, sb = 0.f;

    const int tid    = blockIdx.x * blockDim.x + threadIdx.x;
    const int stride = gridDim.x * blockDim.x;

    int i = tid;

    // ---- main loop: 2-way unrolled (4 independent 16B loads in flight) ----
    for (; i + stride < n4; i += 2 * stride) {
        float4 xv0 = x4[i];
        float4 tv0 = t4[i];
        float4 xv1 = x4[i + stride];
        float4 tv1 = t4[i + stride];

        const float* xp0 = reinterpret_cast<const float*>(&xv0);
        const float* tp0 = reinterpret_cast<const float*>(&tv0);
        const float* xp1 = reinterpret_cast<const float*>(&xv1);
        const float* tp1 = reinterpret_cast<const float*>(&tv1);

        #pragma unroll
        for (int j = 0; j < 4; ++j) ELEM_BODY(xp0[j], tp0[j]);
        #pragma unroll
        for (int j = 0; j < 4; ++j) ELEM_BODY(xp1[j], tp1[j]);
    }

    // ---- tail ----
    for (; i < n4; i += stride) {
        float4 xv = x4[i];
        float4 tv = t4[i];
        const float* xp = reinterpret_cast<const float*>(&xv);
        const float* tp = reinterpret_cast<const float*>(&tv);
        #pragma unroll
        for (int j = 0; j < 4; ++j) ELEM_BODY(xp[j], tp[j]);
    }

    // ---- wave (64-lane) reduction ----
    #pragma unroll
    for (int off = 32; off > 0; off >>= 1) {
        sx  += __shfl_down(sx,  off);
        st  += __shfl_down(st,  off);
        sx2 += __shfl_down(sx2, off);
        sxt += __shfl_down(sxt, off);
        sb  += __shfl_down(sb,  off);
    }

    // ---- block reduction across 4 waves ----
    __shared__ float lds[4][ACC_COUNT];
    int lane = threadIdx.x & 63;
    int wid  = threadIdx.x >> 6;
    if (lane == 0) {
        lds[wid][0] = sx;  lds[wid][1] = st;  lds[wid][2] = sx2;
        lds[wid][3] = sxt; lds[wid][4] = sb;
    }
    __syncthreads();

    if (threadIdx.x < ACC_COUNT) {
        int k = threadIdx.x;
        float v = lds[0][k] + lds[1][k] + lds[2][k] + lds[3][k];
        partials[k * MAX_BLOCKS + blockIdx.x] = v;   // SoA, no atomics
    }
}

__global__ __launch_bounds__(256) void loss_finalize_kernel(
    const float* __restrict__ partials,
    float* __restrict__ out,
    int nblocks)
{
    double a[ACC_COUNT] = {0, 0, 0, 0, 0};

    for (int r = threadIdx.x; r < nblocks; r += blockDim.x) {
        #pragma unroll
        for (int k = 0; k < ACC_COUNT; ++k)
            a[k] += (double)partials[k * MAX_BLOCKS + r];
    }

    #pragma unroll
    for (int off = 32; off > 0; off >>= 1) {
        #pragma unroll
        for (int k = 0; k < ACC_COUNT; ++k)
            a[k] += __shfl_down(a[k], off);
    }

    __shared__ double lds[4][ACC_COUNT];
    int lane = threadIdx.x & 63;
    int wid  = threadIdx.x >> 6;
    if (lane == 0) {
        #pragma unroll
        for (int k = 0; k < ACC_COUNT; ++k) lds[wid][k] = a[k];
    }
    __syncthreads();

    if (threadIdx.x == 0) {
        double sx  = lds[0][0] + lds[1][0] + lds[2][0] + lds[3][0];
        double st  = lds[0][1] + lds[1][1] + lds[2][1] + lds[3][1];
        double sx2 = lds[0][2] + lds[1][2] + lds[2][2] + lds[3][2];
        double sxt = lds[0][3] + lds[1][3] + lds[2][3] + lds[3][3];
        double sb  = lds[0][4] + lds[1][4] + lds[2][4] + lds[3][4];

        const double n = (double)N_TOTAL;
        const double LN2 = 0.6931471805599453;

        // BCE (sb is in log2 space)
        double bce = -(sb * LN2) / n;

        // NCC (Σt² == Σt exactly, since t ∈ {0,1})
        double xm = sx / n;
        double tm = st / n;
        double xs = sqrt((sx2 - sx * sx / n) / (n - 1.0));
        double ts = sqrt((st  - st * st / n) / (n - 1.0));
        double ncc = (sxt - n * xm * tm) / (xs * ts * n);

        // Tversky
        const double beta = 0.1, adding = 1.0;
        double TP = sxt;
        double FP = sx - sxt;
        double FN = st - sxt;
        double tversky = (TP + adding) / (TP + beta * FP + (1.0 - beta) * FN + adding);

        const double alpha = 0.5;
        double res = (1.0 - (alpha * ncc + (1.0 - alpha) * tversky)) * bce;

        out[0] = (float)res;
    }
}

extern "C" void kernel_launch(void* const* d_in, const int* in_sizes, int n_in,
                              void* d_out, int out_size, void* d_ws, size_t ws_size,
                              hipStream_t stream)
{
    const float* x = (const float*)d_in[0];
    const float* t = (const float*)d_in[1];
    float* out = (float*)d_out;
    float* partials = (float*)d_ws;

    int n  = in_sizes[0];
    int n4 = n / 4;

    const int block = 256;
    int grid = (n4 + block - 1) / block;
    if (grid > MAX_BLOCKS) grid = MAX_BLOCKS;

    loss_reduce_kernel<<<grid, block, 0, stream>>>(
        (const float4*)x, (const float4*)t, partials, n4);
    loss_finalize_kernel<<<1, block, 0, stream>>>(partials, out, grid);
}